// Round 10
// baseline (157.369 us; speedup 1.0000x reference)
//
#include <hip/hip_runtime.h>

// Problem constants (B,C,D,H,W) = (2,4,96,160,160)
#define NB 2
#define NC 4
#define ND 96
#define NH 160
#define NW 160

// Math (verified exact rounds 1-9): sy == sz (identical 2D 3x3 kernels),
// depth padding adds only zero slices, sobel(p)-sobel(t) = sobel(q) with
// q = softmax(pred) - onehot(target):
//   loss = sum(gx^2 + 2*gy^2) * SCALE
// separable: d = q[x+1]-q[x-1], s = q[x-1]+2q[x]+q[x+1],
//            gx = d[y-1]+2d[y]+d[y+1], gy = s[y+1]-s[y-1].
//
// Perf history:
//  r4/r5: __launch_bounds__(256,N) VGPR cap -> 128 MB scratch spill. NEVER cap.
//  r2..r6: dur == #same-address-atomicAdds x ~20ns (cross-XCD serialization).
//         r2's "slow shuffles" were actually atomic-bound: 4608x20ns = 92us.
//  r7: plain per-block partial stores + tiny reduce kernel. ~45us kernel.
//  r8/r9: fp16 LDS + band pipeline both plateau ~45us: compiler emits
//         s_waitcnt vmcnt(0) before EVERY s_barrier -> no prefetch survives
//         a __syncthreads. Structural limit of any LDS-staged design.
//  r10 (this): barrier-free wave-streaming. Each wave owns a 62-col strip x
//         20 rows, streams 22 rows with next-row loads prefetched, horizontal
//         halo via __shfl, vertical via rolling registers. No LDS, no
//         barriers, no atomics; 4608 waves keep read queues full.
constexpr int R      = 20;                           // output rows per wave
constexpr int NCHUNK = NH / R;                       // 8
constexpr int NSTRIP = 3;                            // x0 = 0, 62, 124
constexpr int NSLICE = NB * ND;                      // 192
constexpr int NWAVE  = NSLICE * NSTRIP * NCHUNK;     // 4608 wave tasks
constexpr int NPART  = NWAVE;                        // one partial per wave
constexpr float SCALE = 1.0f / (2.0f * 98.0f * 162.0f * 162.0f * 4.0f);

struct Row { float p0, p1, p2, p3; int tg; };

__global__ __launch_bounds__(256) void boundary_loss_kernel(
    const float* __restrict__ pred,   // (B,C,D,H,W) f32
    const int*   __restrict__ target, // (B,D,H,W) i32
    float* __restrict__ part)         // NPART per-wave partials
{
    const int wid  = blockIdx.x * 4 + (threadIdx.x >> 6);
    const int lane = threadIdx.x & 63;

    // decode: chunk fastest (adjacent waves stack vertically -> L2 halo reuse)
    const int chunk = wid & (NCHUNK - 1);
    const int tmp   = wid >> 3;
    const int strip = tmp % NSTRIP;
    const int slice = tmp / NSTRIP;                  // b*ND + d
    const int b     = slice / ND;
    const int d     = slice - b * ND;

    const int  x    = strip * 62 + lane - 1;
    const bool colv = (x >= 0) && (x < NW);
    const bool outm = (lane >= 1) && (lane <= 62) && (x < NW);
    const int  xc   = min(max(x, 0), NW - 1);
    const int  y0   = chunk * R;

    const size_t cs    = (size_t)ND * NH * NW;       // class stride
    const size_t pbase = ((size_t)b * NC * ND + d) * (size_t)(NH * NW);
    const size_t tbase = ((size_t)b * ND + d) * (size_t)(NH * NW);
    const float* P = pred + pbase + xc;
    const int*   T = target + tbase + xc;

    auto ld = [&](int t) {
        Row r;
        const int gy  = y0 - 1 + t;
        const int gyc = min(max(gy, 0), NH - 1);
        const size_t o = (size_t)gyc * NW;
        r.p0 = P[o];
        r.p1 = P[o + cs];
        r.p2 = P[o + 2 * cs];
        r.p3 = P[o + 3 * cs];
        r.tg = T[o];
        return r;
    };

    float smm0 = 0.f, sm0 = 0.f, dmm0 = 0.f, dm0 = 0.f;
    float smm1 = 0.f, sm1 = 0.f, dmm1 = 0.f, dm1 = 0.f;
    float smm2 = 0.f, sm2 = 0.f, dmm2 = 0.f, dm2 = 0.f;
    float smm3 = 0.f, sm3 = 0.f, dmm3 = 0.f, dm3 = 0.f;
    float acc = 0.f;

    Row cur = ld(0);                                  // prefetch row 0
    #pragma unroll
    for (int t = 0; t < R + 2; ++t) {
        Row nxt;
        if (t < R + 1) nxt = ld(t + 1);               // issue next row early

        // softmax(cur) - onehot (masked outside the image)
        const int  gy    = y0 - 1 + t;
        const bool valid = colv && (gy >= 0) && (gy < NH);
        float q0 = 0.f, q1 = 0.f, q2 = 0.f, q3 = 0.f;
        if (valid) {
            const float m  = fmaxf(fmaxf(cur.p0, cur.p1), fmaxf(cur.p2, cur.p3));
            const float e0 = __expf(cur.p0 - m);
            const float e1 = __expf(cur.p1 - m);
            const float e2 = __expf(cur.p2 - m);
            const float e3 = __expf(cur.p3 - m);
            const float inv = __builtin_amdgcn_rcpf(e0 + e1 + e2 + e3);
            q0 = e0 * inv - (cur.tg == 0 ? 1.f : 0.f);
            q1 = e1 * inv - (cur.tg == 1 ? 1.f : 0.f);
            q2 = e2 * inv - (cur.tg == 2 ? 1.f : 0.f);
            q3 = e3 * inv - (cur.tg == 3 ? 1.f : 0.f);
        }

        float rowacc = 0.f;
#define CLS(Q, smm, sm, dmm, dm)                                          \
        do {                                                              \
            const float ql = __shfl_up(Q, 1, 64);                         \
            const float qr = __shfl_down(Q, 1, 64);                       \
            const float sn = ql + 2.f * (Q) + qr;                         \
            const float dn = qr - ql;                                     \
            if (t >= 2) {                                                 \
                const float gx  = dmm + 2.f * dm + dn;                    \
                const float gyv = sn - smm;                               \
                rowacc += gx * gx + 2.f * gyv * gyv;                      \
            }                                                             \
            smm = sm; sm = sn; dmm = dm; dm = dn;                         \
        } while (0)

        CLS(q0, smm0, sm0, dmm0, dm0);
        CLS(q1, smm1, sm1, dmm1, dm1);
        CLS(q2, smm2, sm2, dmm2, dm2);
        CLS(q3, smm3, sm3, dmm3, dm3);
#undef CLS
        if (t >= 2 && outm) acc += rowacc;
        cur = nxt;
    }

    // wave reduction -> one plain store per wave (no LDS, no atomics)
    #pragma unroll
    for (int off = 32; off > 0; off >>= 1)
        acc += __shfl_down(acc, off, 64);
    if (lane == 0) part[wid] = acc;
}

__global__ __launch_bounds__(256) void reduce_partials_kernel(
    const float* __restrict__ part, float* __restrict__ out)
{
    const int tid = threadIdx.x;
    float s = 0.f;
    #pragma unroll
    for (int i = 0; i < NPART / 256; ++i)     // 18 loads, coalesced
        s += part[tid + i * 256];
    #pragma unroll
    for (int off = 32; off > 0; off >>= 1)
        s += __shfl_down(s, off, 64);
    __shared__ float wsum[4];
    if ((tid & 63) == 0) wsum[tid >> 6] = s;
    __syncthreads();
    if (tid == 0)
        out[0] = (wsum[0] + wsum[1] + wsum[2] + wsum[3]) * SCALE;
}

extern "C" void kernel_launch(void* const* d_in, const int* in_sizes, int n_in,
                              void* d_out, int out_size, void* d_ws, size_t ws_size,
                              hipStream_t stream) {
    const float* pred   = (const float*)d_in[0];
    const int*   target = (const int*)d_in[1];
    float*       out    = (float*)d_out;
    float*       part   = (float*)d_ws;      // NPART*4 = 18 KB of scratch

    boundary_loss_kernel<<<NWAVE / 4, 256, 0, stream>>>(pred, target, part);
    reduce_partials_kernel<<<1, 256, 0, stream>>>(part, out);
}